// Round 5
// baseline (2164.464 us; speedup 1.0000x reference)
//
#include <hip/hip_runtime.h>
#include <hip/hip_bf16.h>
#include <stdint.h>

// Problem constants: B=4, S=512, E=768, H=12, D=64, L=12, FF=3072, M = B*S = 2048
#define LAYERS 12
#define M_ROWS 2048
#define E_DIM 768
#define FF_DIM 3072
#define QKV_DIM 2304
#define SCALE_INV 0.036084391824351615f  // 1/sqrt(768)

typedef __hip_bfloat16 bf16;
typedef __attribute__((ext_vector_type(8))) __bf16 bf16x8;
typedef __attribute__((ext_vector_type(4))) float f32x4;

__device__ __forceinline__ float bf2f(bf16 v) { return __bfloat162float(v); }
__device__ __forceinline__ bf16 f2bf(float v) { return __float2bfloat16(v); }

__device__ __forceinline__ float gelu_f(float x) {
  return 0.5f * x * (1.0f + erff(x * 0.70710678118654752f));
}

// async global->LDS, 16 bytes per lane. LDS dest must be wave-uniform base;
// HW adds lane*16. (learn_hip m97 pattern)
__device__ __forceinline__ void async16(const bf16* g, bf16* l) {
  __builtin_amdgcn_global_load_lds(
      (const __attribute__((address_space(1))) void*)g,
      (__attribute__((address_space(3))) void*)l, 16, 0, 0);
}

// ---------------------------------------------------------------------------
// Batched weight transpose+convert for ALL layers (hoisted): fp32 [K][N] ->
// bf16 [N][K]. 64x64 tiles; write rows are 128 B fully coalesced (fixes the
// 2x write amplification measured in round 3: 166 MB written vs 85 MB ideal).
// For Wqkv the output columns are PERMUTED to n' = t*768 + h*64 + d (source
// n = h*192 + d*3 + t) so the QKV GEMM epilogue writes contiguous d-runs.
// ---------------------------------------------------------------------------
__global__ __launch_bounds__(256) void transpose_all_k(
    const float* __restrict__ Wqkv, const float* __restrict__ Wp,
    const float* __restrict__ W1, const float* __restrict__ W2,
    bf16* __restrict__ tq, bf16* __restrict__ tp,
    bf16* __restrict__ t1, bf16* __restrict__ t2)
{
  __shared__ float T[64][65];
  int l = blockIdx.y;
  int bid = blockIdx.x;
  const float* src; bf16* dst; int K, N, tile, perm;
  if (bid < 432)       { src = Wqkv + (size_t)l * 768 * 2304; dst = tq + (size_t)l * 768 * 2304; K = 768;  N = 2304; tile = bid;        perm = 1; }
  else if (bid < 576)  { src = Wp   + (size_t)l * 768 * 768;  dst = tp + (size_t)l * 768 * 768;  K = 768;  N = 768;  tile = bid - 432;  perm = 0; }
  else if (bid < 1152) { src = W1   + (size_t)l * 768 * 3072; dst = t1 + (size_t)l * 768 * 3072; K = 768;  N = 3072; tile = bid - 576;  perm = 0; }
  else                 { src = W2   + (size_t)l * 3072 * 768; dst = t2 + (size_t)l * 3072 * 768; K = 3072; N = 768;  tile = bid - 1152; perm = 0; }
  int tilesN = N >> 6;
  int tk = tile / tilesN, tn = tile - tk * tilesN;
  int k0 = tk << 6, n0 = tn << 6;
  int t = threadIdx.x;
  int lrow = t >> 4, lcol = (t & 15) * 4;
#pragma unroll
  for (int it = 0; it < 4; it++) {
    int row = it * 16 + lrow;
    const float4 v4 = *(const float4*)&src[(size_t)(k0 + row) * N + n0 + lcol];
    T[row][lcol] = v4.x; T[row][lcol + 1] = v4.y;
    T[row][lcol + 2] = v4.z; T[row][lcol + 3] = v4.w;
  }
  __syncthreads();
  int kc = (t & 7) * 8, nb = t >> 3;
#pragma unroll
  for (int it = 0; it < 2; it++) {
    int nrow = it * 32 + nb;
    int n = n0 + nrow;
    int ncol = n;
    if (perm) {
      int h = n / 192;
      int rm = n - h * 192;
      int d = rm / 3;
      int t3 = rm - d * 3;
      ncol = t3 * 768 + h * 64 + d;
    }
    union { bf16 h8[8]; uint4 v; } u;
#pragma unroll
    for (int j = 0; j < 8; j++) u.h8[j] = f2bf(T[kc + j][nrow]);
    *(uint4*)&dst[(size_t)ncol * K + k0 + kc] = u.v;   // 16 B coalesced
  }
}

// ---------------------------------------------------------------------------
// LayerNorm over last dim (768). One block (256 thr) per row.
// ---------------------------------------------------------------------------
template<int OUT_BF16, int NADD, int NPART>
__global__ __launch_bounds__(256) void ln_k(
    const float* __restrict__ in, const float* __restrict__ gamma,
    const float* __restrict__ beta, const float* __restrict__ add0,
    const float* __restrict__ add1, void* __restrict__ outp)
{
  int row = blockIdx.x, tid = threadIdx.x;
  size_t rb = (size_t)row * 768;
  float v[3]; float s = 0.f, sq = 0.f;
#pragma unroll
  for (int j = 0; j < 3; j++) {
    int c = tid + j * 256;
    float x = in[rb + c];
    if (NPART == 2) x += in[(size_t)M_ROWS * 768 + rb + c];
    v[j] = x;
    s += x; sq += x * x;
  }
#pragma unroll
  for (int off = 32; off; off >>= 1) {
    s += __shfl_xor(s, off);
    sq += __shfl_xor(sq, off);
  }
  __shared__ float red[8];
  int wv = tid >> 6;
  if ((tid & 63) == 0) { red[wv] = s; red[4 + wv] = sq; }
  __syncthreads();
  s  = red[0] + red[1] + red[2] + red[3];
  sq = red[4] + red[5] + red[6] + red[7];
  float mean = s * (1.0f / 768.0f);
  float var  = sq * (1.0f / 768.0f) - mean * mean;
  float rstd = rsqrtf(var + 1e-5f);
#pragma unroll
  for (int j = 0; j < 3; j++) {
    int c = tid + j * 256;
    float val = (v[j] - mean) * rstd * gamma[c] + beta[c];
    if (NADD >= 1) val += add0[rb + c];
    if (NADD >= 2) val += add1[rb + c];
    if (OUT_BF16) ((bf16*)outp)[rb + c] = f2bf(val);
    else          ((float*)outp)[rb + c] = val;
  }
}

// ---------------------------------------------------------------------------
// Fused double-LayerNorm: y = LN_A(sum partials) [+add0 +add1] -> out1 (fp32),
// then (if WRITE2) h = LN_B(y) -> out2 (bf16).
// ---------------------------------------------------------------------------
template<int NADD, int NPART, int WRITE2>
__global__ __launch_bounds__(256) void lnln_k(
    const float* __restrict__ in, const float* __restrict__ gA,
    const float* __restrict__ bA, const float* __restrict__ add0,
    const float* __restrict__ add1, float* __restrict__ out1,
    const float* __restrict__ gB, const float* __restrict__ bB,
    bf16* __restrict__ out2)
{
  int row = blockIdx.x, tid = threadIdx.x;
  size_t rb = (size_t)row * 768;
  __shared__ float red[8];
  int wv = tid >> 6;

  float v[3]; float s = 0.f, sq = 0.f;
#pragma unroll
  for (int j = 0; j < 3; j++) {
    int c = tid + j * 256;
    float x = in[rb + c];
    if (NPART == 2) x += in[(size_t)M_ROWS * 768 + rb + c];
    v[j] = x;
    s += x; sq += x * x;
  }
#pragma unroll
  for (int off = 32; off; off >>= 1) {
    s += __shfl_xor(s, off);
    sq += __shfl_xor(sq, off);
  }
  if ((tid & 63) == 0) { red[wv] = s; red[4 + wv] = sq; }
  __syncthreads();
  s  = red[0] + red[1] + red[2] + red[3];
  sq = red[4] + red[5] + red[6] + red[7];
  float mean = s * (1.0f / 768.0f);
  float var  = sq * (1.0f / 768.0f) - mean * mean;
  float rstd = rsqrtf(var + 1e-5f);

  float y[3]; float s2 = 0.f, sq2 = 0.f;
#pragma unroll
  for (int j = 0; j < 3; j++) {
    int c = tid + j * 256;
    float t = (v[j] - mean) * rstd * gA[c] + bA[c];
    if (NADD >= 1) t += add0[rb + c];
    if (NADD >= 2) t += add1[rb + c];
    y[j] = t;
    out1[rb + c] = t;
    s2 += t; sq2 += t * t;
  }
  if (WRITE2) {
#pragma unroll
    for (int off = 32; off; off >>= 1) {
      s2 += __shfl_xor(s2, off);
      sq2 += __shfl_xor(sq2, off);
    }
    __syncthreads();
    if ((tid & 63) == 0) { red[wv] = s2; red[4 + wv] = sq2; }
    __syncthreads();
    s2  = red[0] + red[1] + red[2] + red[3];
    sq2 = red[4] + red[5] + red[6] + red[7];
    float mean2 = s2 * (1.0f / 768.0f);
    float var2  = sq2 * (1.0f / 768.0f) - mean2 * mean2;
    float rstd2 = rsqrtf(var2 + 1e-5f);
#pragma unroll
    for (int j = 0; j < 3; j++) {
      int c = tid + j * 256;
      out2[rb + c] = f2bf((y[j] - mean2) * rstd2 * gB[c] + bB[c]);
    }
  }
}

// ---------------------------------------------------------------------------
// bf16 MFMA GEMM, 128x64 tile, 128 threads = 2 waves; wave w owns the FULL
// 64x64 quadrant rows [w*64, w*64+64) x 64 cols -> acc[4][4], 16 MFMA and
// only 8 ds_read_b128 per K-step per wave (m97's 4-reads-per-8-MFMA ratio;
// the 4-wave 128x64 variant was 6/8 — LDS read port is the ceiling).
// Grids stay large (round-2 lesson): QKV 576, proj/FF2 384, FF1 768 blocks.
// LDS 24 KB -> 6 blocks/CU = 12 waves/CU.
// Staging: global_load_lds dwordx4, 6 issues/thread/K-step, double-buffered.
// OUT_MODE: 0 = fp32 out (NSPLIT partials), 1 = bf16, 2 = bf16+GELU,
//           3 = split-QKV out (PERMUTED n = t*768 + h*64 + d); q,k as
//           [B][H][S][D], v TRANSPOSED [B][H][D][S].
// ---------------------------------------------------------------------------
template<int OUT_MODE, int NSPLIT>
__global__ __launch_bounds__(128) void gemm5_k(
    const bf16* __restrict__ A, const bf16* __restrict__ BT,
    const float* __restrict__ bias, void* __restrict__ Cout,
    bf16* __restrict__ qo, bf16* __restrict__ ko, bf16* __restrict__ vo,
    int N, int K)
{
  __shared__ __align__(16) bf16 Als[2][128 * 32];
  __shared__ __align__(16) bf16 Bls[2][64 * 32];
  int tid = threadIdx.x;
  int lane = tid & 63, w = tid >> 6;
  int l15 = lane & 15, l4 = lane >> 4;
  int Nt = N >> 6;
  int mt = blockIdx.x / Nt, ntile = blockIdx.x - mt * Nt;
  int m0 = mt << 7, n0 = ntile << 6;
  int sp = (NSPLIT > 1) ? blockIdx.y : 0;
  int Kc = K / NSPLIT;
  int kbeg = sp * Kc;
  int nsteps = Kc >> 5;
  int sr = tid >> 2;            // staging row 0..31
  int sc = (tid & 3) * 8;       // staging col (x8 elems = 16B)
  const bf16* a_src = A + (size_t)(m0 + sr) * K + kbeg + sc;
  const bf16* b_src = BT + (size_t)(n0 + sr) * K + kbeg + sc;

  f32x4 acc[4][4] = {};

#define STAGE5(buf)                                                  \
  do {                                                               \
    async16(a_src,                   &Als[buf][w * 512]);            \
    async16(a_src + (size_t)32 * K,  &Als[buf][1024 + w * 512]);     \
    async16(a_src + (size_t)64 * K,  &Als[buf][2048 + w * 512]);     \
    async16(a_src + (size_t)96 * K,  &Als[buf][3072 + w * 512]);     \
    async16(b_src,                   &Bls[buf][w * 512]);            \
    async16(b_src + (size_t)32 * K,  &Bls[buf][1024 + w * 512]);     \
  } while (0)

  STAGE5(0);
  __syncthreads();   // drains vmcnt(0): buf0 ready

  int cur = 0;
  for (int ks = 0; ks < nsteps; ks++) {
    if (ks + 1 < nsteps) {
      a_src += 32; b_src += 32;
      STAGE5(cur ^ 1);
    }
    bf16x8 af[4], bfr[4];
#pragma unroll
    for (int i = 0; i < 4; i++)
      af[i] = *(const bf16x8*)&Als[cur][(w * 64 + i * 16 + l15) * 32 + l4 * 8];
#pragma unroll
    for (int j = 0; j < 4; j++)
      bfr[j] = *(const bf16x8*)&Bls[cur][(j * 16 + l15) * 32 + l4 * 8];
#pragma unroll
    for (int i = 0; i < 4; i++)
#pragma unroll
      for (int j = 0; j < 4; j++)
        acc[i][j] = __builtin_amdgcn_mfma_f32_16x16x32_bf16(af[i], bfr[j], acc[i][j], 0, 0, 0);
    __syncthreads();   // next buffer ready + all reads done
    cur ^= 1;
  }
#undef STAGE5

  // epilogue
#pragma unroll
  for (int i = 0; i < 4; i++) {
    int mbase = m0 + w * 64 + i * 16 + (l4 << 2);
#pragma unroll
    for (int j = 0; j < 4; j++) {
      int n = n0 + j * 16 + l15;
      if (OUT_MODE == 3) {
        // permuted n = t*768 + h*64 + d
        int t = (n >= 1536) ? 2 : (n >= 768 ? 1 : 0);
        int rm = n - t * 768;
        int h = rm >> 6;
        int d = rm & 63;
        float bvs = bias[h * 192 + d * 3 + t];
#pragma unroll
        for (int rg = 0; rg < 4; rg++) {
          int m = mbase + rg;
          float val = acc[i][j][rg] + bvs;
          int b = m >> 9, sIdx = m & 511;
          int bh = b * 12 + h;
          if (t == 2)
            vo[(size_t)((bh << 6) + d) * 512 + sIdx] = f2bf(val);       // [B][H][D][S]
          else {
            bf16* dsts = (t == 0) ? qo : ko;
            dsts[(size_t)((bh << 9) + sIdx) * 64 + d] = f2bf(val);      // [B][H][S][D]
          }
        }
      } else {
        float bvs = (NSPLIT == 1 || sp == 0) ? bias[n] : 0.0f;
#pragma unroll
        for (int rg = 0; rg < 4; rg++) {
          int m = mbase + rg;
          float val = acc[i][j][rg] + bvs;
          if (OUT_MODE == 0)
            ((float*)Cout)[(size_t)sp * M_ROWS * N + (size_t)m * N + n] = val;
          else if (OUT_MODE == 1)
            ((bf16*)Cout)[(size_t)m * N + n] = f2bf(val);
          else
            ((bf16*)Cout)[(size_t)m * N + n] = f2bf(gelu_f(val));
        }
      }
    }
  }
}

// ---------------------------------------------------------------------------
// MFMA flash attention. Block = one (b,h) x 64 query rows; 4 waves x 16 rows.
// q,k: bf16 [B][H][S][D];  vT: bf16 [B][H][D][S];  o: bf16 [B*S][768].
// att = softmax(q.k) / sqrt(768)  (scale after softmax — faithful).
// Online softmax over 8 key-tiles of 64. K/VT staged via global_load_lds.
// ---------------------------------------------------------------------------
#define PSTR 80   // P staging row stride (bf16 elems): 160B rows -> 4-way max conflict
__global__ __launch_bounds__(256) void attn_k(
    const bf16* __restrict__ q, const bf16* __restrict__ k,
    const bf16* __restrict__ vT, bf16* __restrict__ o)
{
  __shared__ __align__(16) bf16 Kls[64 * 64];        // [key][d]
  __shared__ __align__(16) bf16 Vls[64 * 64];        // [d][key]
  __shared__ __align__(16) bf16 Pls[4][16 * PSTR];   // per-wave P transpose buf
  int tid = threadIdx.x;
  int lane = tid & 63, w = tid >> 6;
  int l15 = lane & 15, l4 = lane >> 4;
  int qt = blockIdx.x & 7;
  int bh = blockIdx.x >> 3;
  size_t base = (size_t)bh * 32768;    // 512*64

  const bf16* qrowp = q + base + (size_t)(qt * 64 + w * 16 + l15) * 64 + l4 * 8;
  bf16x8 qf0 = *(const bf16x8*)qrowp;
  bf16x8 qf1 = *(const bf16x8*)(qrowp + 32);

  int rr = tid >> 3, cc = (tid & 7) * 8;
  const bf16* ksrc = k + base + (size_t)rr * 64 + cc;
  const bf16* vsrc = vT + base + (size_t)rr * 512 + cc;

  float mrow[4] = {-1e30f, -1e30f, -1e30f, -1e30f};
  float lsum[4] = {0.f, 0.f, 0.f, 0.f};
  f32x4 Oacc[4] = {};
  const f32x4 zed = {0.f, 0.f, 0.f, 0.f};
  bf16* pw = &Pls[w][0];

  for (int kt = 0; kt < 8; kt++) {
    __syncthreads();
    async16(ksrc + (size_t)kt * 4096,          &Kls[w * 512]);
    async16(ksrc + (size_t)kt * 4096 + 2048,   &Kls[2048 + w * 512]);
    async16(vsrc + kt * 64,                    &Vls[w * 512]);
    async16(vsrc + kt * 64 + (size_t)32 * 512, &Vls[2048 + w * 512]);
    __syncthreads();
    f32x4 e[4];
#pragma unroll
    for (int jt = 0; jt < 4; jt++) {
      bf16x8 kf0 = *(const bf16x8*)&Kls[(jt * 16 + l15) * 64 + l4 * 8];
      bf16x8 kf1 = *(const bf16x8*)&Kls[(jt * 16 + l15) * 64 + l4 * 8 + 32];
      e[jt] = __builtin_amdgcn_mfma_f32_16x16x32_bf16(qf0, kf0, zed, 0, 0, 0);
      e[jt] = __builtin_amdgcn_mfma_f32_16x16x32_bf16(qf1, kf1, e[jt], 0, 0, 0);
    }
    float al[4];
#pragma unroll
    for (int rg = 0; rg < 4; rg++) {
      float mn = fmaxf(fmaxf(e[0][rg], e[1][rg]), fmaxf(e[2][rg], e[3][rg]));
#pragma unroll
      for (int off = 1; off < 16; off <<= 1) mn = fmaxf(mn, __shfl_xor(mn, off));
      float mnew = fmaxf(mrow[rg], mn);
      al[rg] = __expf(mrow[rg] - mnew);
      mrow[rg] = mnew;
    }
    float rs[4] = {0.f, 0.f, 0.f, 0.f};
#pragma unroll
    for (int jt = 0; jt < 4; jt++)
#pragma unroll
      for (int rg = 0; rg < 4; rg++) {
        float p = __expf(e[jt][rg] - mrow[rg]);
        rs[rg] += p;
        pw[(l4 * 4 + rg) * PSTR + jt * 16 + l15] = f2bf(p);
      }
#pragma unroll
    for (int rg = 0; rg < 4; rg++) {
#pragma unroll
      for (int off = 1; off < 16; off <<= 1) rs[rg] += __shfl_xor(rs[rg], off);
      lsum[rg] = lsum[rg] * al[rg] + rs[rg];
    }
#pragma unroll
    for (int dt = 0; dt < 4; dt++)
#pragma unroll
      for (int rg = 0; rg < 4; rg++) Oacc[dt][rg] *= al[rg];
    bf16x8 pf0 = *(const bf16x8*)&pw[l15 * PSTR + l4 * 8];
    bf16x8 pf1 = *(const bf16x8*)&pw[l15 * PSTR + l4 * 8 + 32];
#pragma unroll
    for (int dt = 0; dt < 4; dt++) {
      bf16x8 vf0 = *(const bf16x8*)&Vls[(dt * 16 + l15) * 64 + l4 * 8];
      bf16x8 vf1 = *(const bf16x8*)&Vls[(dt * 16 + l15) * 64 + l4 * 8 + 32];
      Oacc[dt] = __builtin_amdgcn_mfma_f32_16x16x32_bf16(pf0, vf0, Oacc[dt], 0, 0, 0);
      Oacc[dt] = __builtin_amdgcn_mfma_f32_16x16x32_bf16(pf1, vf1, Oacc[dt], 0, 0, 0);
    }
  }
  int b = bh / 12, h = bh - b * 12;
#pragma unroll
  for (int rg = 0; rg < 4; rg++) {
    int qrow = qt * 64 + w * 16 + l4 * 4 + rg;
    float inv = SCALE_INV / lsum[rg];
    size_t rowoff = (size_t)(b * 512 + qrow) * 768 + h * 64;
#pragma unroll
    for (int dt = 0; dt < 4; dt++)
      o[rowoff + dt * 16 + l15] = f2bf(Oacc[dt][rg] * inv);
  }
}

// ---------------------------------------------------------------------------
extern "C" void kernel_launch(void* const* d_in, const int* in_sizes, int n_in,
                              void* d_out, int out_size, void* d_ws, size_t ws_size,
                              hipStream_t stream)
{
  const float* x    = (const float*)d_in[0];
  const float* Wqkv = (const float*)d_in[1];
  const float* bqkv = (const float*)d_in[2];
  const float* Wp   = (const float*)d_in[3];
  const float* bp   = (const float*)d_in[4];
  const float* W1   = (const float*)d_in[5];
  const float* b1   = (const float*)d_in[6];
  const float* W2   = (const float*)d_in[7];
  const float* b2   = (const float*)d_in[8];
  const float* g1  = (const float*)d_in[9];
  const float* be1 = (const float*)d_in[10];
  const float* g2  = (const float*)d_in[11];
  const float* be2 = (const float*)d_in[12];
  const float* g3  = (const float*)d_in[13];
  const float* be3 = (const float*)d_in[14];
  const float* g4  = (const float*)d_in[15];
  const float* be4 = (const float*)d_in[16];
  float* xout = (float*)d_out;

  char* ws = (char*)d_ws;
  size_t off = 0;
  auto alloc = [&](size_t bytes) -> char* {
    char* p = ws + off;
    off += (bytes + 255) & ~(size_t)255;
    return p;
  };
  const size_t NTOK = (size_t)M_ROWS * E_DIM;
  bf16*  qb  = (bf16*)alloc(NTOK * 2);
  bf16*  kb  = (bf16*)alloc(NTOK * 2);
  bf16*  vb  = (bf16*)alloc(NTOK * 2);   // holds V^T [B][H][D][S]
  bf16*  hb  = (bf16*)alloc(NTOK * 2);
  bf16*  ob  = (bf16*)alloc(NTOK * 2);
  bf16*  f1b = (bf16*)alloc((size_t)M_ROWS * FF_DIM * 2);
  float* tmp = (float*)alloc(NTOK * 4 * 2);   // 2 split-K fp32 partials
  float* r1  = (float*)alloc(NTOK * 4);
  bf16*  tq  = (bf16*)alloc((size_t)LAYERS * 768 * 2304 * 2);
  bf16*  tp  = (bf16*)alloc((size_t)LAYERS * 768 * 768 * 2);
  bf16*  t1  = (bf16*)alloc((size_t)LAYERS * 768 * 3072 * 2);
  bf16*  t2  = (bf16*)alloc((size_t)LAYERS * 3072 * 768 * 2);
  if (off > ws_size) {
    hipMemsetAsync(d_out, 0x7f, (size_t)out_size * 4, stream);
    return;
  }

  // all weight transposes up front (one dispatch, 12 layers)
  transpose_all_k<<<dim3(1728, LAYERS), 256, 0, stream>>>(
      Wqkv, Wp, W1, W2, tq, tp, t1, t2);

  hipMemcpyAsync(d_out, x, (size_t)out_size * 4, hipMemcpyDeviceToDevice, stream);

  // layer-0 pre-LN
  ln_k<1, 0, 1><<<2048, 256, 0, stream>>>(xout, g1, be1, nullptr, nullptr, hb);

  for (int l = 0; l < LAYERS; l++) {
    const bf16* tq_l = tq + (size_t)l * 768 * 2304;
    const bf16* tp_l = tp + (size_t)l * 768 * 768;
    const bf16* t1_l = t1 + (size_t)l * 768 * 3072;
    const bf16* t2_l = t2 + (size_t)l * 3072 * 768;

    // QKV: M=2048,N=2304,K=768 -> 16x36 = 576 blocks (128 thr)
    gemm5_k<3, 1><<<dim3(16 * 36, 1), 128, 0, stream>>>(
        hb, tq_l, bqkv + (size_t)l * 2304, nullptr, qb, kb, vb, 2304, 768);
    attn_k<<<384, 256, 0, stream>>>(qb, kb, vb, ob);
    // proj: M=2048,N=768,K=768 split-K 2 -> 384 blocks, fp32 partials
    gemm5_k<0, 2><<<dim3(16 * 12, 2), 128, 0, stream>>>(
        ob, tp_l, bp + (size_t)l * 768, tmp, nullptr, nullptr, nullptr, 768, 768);
    // r1 = LN(tmp)+xout ; hb = bf16(LN(r1))   (fused)
    lnln_k<1, 2, 1><<<2048, 256, 0, stream>>>(
        tmp, g2 + l * 768, be2 + l * 768, xout, nullptr, r1,
        g3 + l * 768, be3 + l * 768, hb);
    // FF1: M=2048,N=3072,K=768 -> 16x48 = 768 blocks
    gemm5_k<2, 1><<<dim3(16 * 48, 1), 128, 0, stream>>>(
        hb, t1_l, b1 + (size_t)l * 3072, f1b, nullptr, nullptr, nullptr, 3072, 768);
    // FF2: M=2048,N=768,K=3072 split-K 2 -> 384 blocks, fp32 partials
    gemm5_k<0, 2><<<dim3(16 * 12, 2), 128, 0, stream>>>(
        f1b, t2_l, b2 + (size_t)l * 768, tmp, nullptr, nullptr, nullptr, 768, 3072);
    // xout = LN(tmp)+r1+xout ; hb = bf16(LN(xout)) with NEXT layer's ln1 (fused)
    if (l + 1 < LAYERS) {
      lnln_k<2, 2, 1><<<2048, 256, 0, stream>>>(
          tmp, g4 + l * 768, be4 + l * 768, r1, xout, xout,
          g1 + (l + 1) * 768, be1 + (l + 1) * 768, hb);
    } else {
      lnln_k<2, 2, 0><<<2048, 256, 0, stream>>>(
          tmp, g4 + l * 768, be4 + l * 768, r1, xout, xout,
          nullptr, nullptr, nullptr);
    }
  }
}